// Round 2
// baseline (850.571 us; speedup 1.0000x reference)
//
#include <hip/hip_runtime.h>

#define NB 512      // batch
#define NS 512      // seq len
#define NI 64       // input dim
#define NC 4        // context dim
#define NH 100      // hidden dim
#define NO 7        // output dim
#define IC 68       // NI + NC
#define WROW 168    // IC + NH (weight row length)
#define KH 112      // hidden dim padded to 4*28
#define QH 28       // per-quarter hidden slice
#define QX 16       // per-quarter input slice

// One block per batch row. 256 threads: tid = (jj<<2)|q.
//   q  = K-quarter (0..3), jj = output-pair (0..63) -> outputs j0=2jj, j1=2jj+1 (valid j<100)
// Weights held in registers per thread; h/g/x_t staged in LDS (broadcast reads).
__global__ __launch_bounds__(256, 2) void agent_scan(
    const float* __restrict__ x,     // [B,S,I]
    const float* __restrict__ ctx,   // [C]
    const float* __restrict__ Wf_w,  // [H,168]
    const float* __restrict__ Wf_b,  // [H]
    const float* __restrict__ Wh_w,  // [H,168]
    const float* __restrict__ Wh_b,  // [H]
    const float* __restrict__ ro_w,  // [O,H]
    const float* __restrict__ ro_b,  // [O]
    float* __restrict__ out)         // [B*O] ++ [B,S,H]
{
    const int b   = blockIdx.x;
    const int tid = threadIdx.x;
    const int q   = tid & 3;
    const int jj  = tid >> 2;
    const int j0  = 2 * jj;
    const bool act = (jj < NH / 2);   // owns two valid outputs

    __shared__ __align__(16) float h_buf[2][KH];
    __shared__ __align__(16) float g_buf[KH];
    __shared__ __align__(16) float x_buf[2][NI];

    // zero LDS (pads must be 0.0, not poison: 0*NaN = NaN)
    for (int i = tid; i < 2 * KH; i += 256) (&h_buf[0][0])[i] = 0.f;
    for (int i = tid; i < KH; i += 256) g_buf[i] = 0.f;

    // ---- load per-thread weight slices into registers ----
    float wfx[2][QX], whx[2][QX], wfh[2][QH], whh[2][QH];
    float ctxf[2], ctxh[2];
    const float c0 = ctx[0], c1 = ctx[1], c2 = ctx[2], c3 = ctx[3];
    #pragma unroll
    for (int o = 0; o < 2; ++o) {
        const int j = 2 * jj + o;
        if (j < NH) {
            const float* rf = Wf_w + (size_t)j * WROW;
            const float* rh = Wh_w + (size_t)j * WROW;
            #pragma unroll
            for (int i = 0; i < QX; ++i) {
                wfx[o][i] = rf[q * QX + i];
                whx[o][i] = rh[q * QX + i];
            }
            #pragma unroll
            for (int i = 0; i < QH; ++i) {
                const int k = q * QH + i;
                wfh[o][i] = (k < NH) ? rf[IC + k] : 0.f;
                whh[o][i] = (k < NH) ? rh[IC + k] : 0.f;
            }
            ctxf[o] = Wf_b[j] + rf[64] * c0 + rf[65] * c1 + rf[66] * c2 + rf[67] * c3;
            ctxh[o] = Wh_b[j] + rh[64] * c0 + rh[65] * c1 + rh[66] * c2 + rh[67] * c3;
        } else {
            #pragma unroll
            for (int i = 0; i < QX; ++i) { wfx[o][i] = 0.f; whx[o][i] = 0.f; }
            #pragma unroll
            for (int i = 0; i < QH; ++i) { wfh[o][i] = 0.f; whh[o][i] = 0.f; }
            ctxf[o] = 0.f; ctxh[o] = 0.f;
        }
    }

    // stage x_0
    const float* xrow = x + (size_t)b * NS * NI;
    if (tid < 16) {
        float4 v = *(const float4*)(xrow + tid * 4);
        *(float4*)&x_buf[0][tid * 4] = v;
    }
    __syncthreads();

    float* hid = out + NB * NO + (size_t)b * NS * NH;

    for (int t = 0; t < NS; ++t) {
        const int hb = t & 1;

        // prefetch x_{t+1} into registers (covers HBM latency under compute)
        float4 xpre = make_float4(0.f, 0.f, 0.f, 0.f);
        if (tid < 16 && t + 1 < NS)
            xpre = *(const float4*)(xrow + (size_t)(t + 1) * NI + tid * 4);

        // ---- phase A: z_f = Wfx.x + Wfh.h (partial per quarter); ph kept partial ----
        float pf0 = 0.f, pf1 = 0.f, ph0 = 0.f, ph1 = 0.f;
        #pragma unroll
        for (int u = 0; u < QX; u += 4) {
            const float4 xv = *(const float4*)&x_buf[hb][q * QX + u];
            pf0 += wfx[0][u] * xv.x + wfx[0][u+1] * xv.y + wfx[0][u+2] * xv.z + wfx[0][u+3] * xv.w;
            pf1 += wfx[1][u] * xv.x + wfx[1][u+1] * xv.y + wfx[1][u+2] * xv.z + wfx[1][u+3] * xv.w;
            ph0 += whx[0][u] * xv.x + whx[0][u+1] * xv.y + whx[0][u+2] * xv.z + whx[0][u+3] * xv.w;
            ph1 += whx[1][u] * xv.x + whx[1][u+1] * xv.y + whx[1][u+2] * xv.z + whx[1][u+3] * xv.w;
        }
        float pu0 = 0.f, pu1 = 0.f;
        #pragma unroll
        for (int u = 0; u < QH; u += 4) {
            const float4 hv = *(const float4*)&h_buf[hb][q * QH + u];
            pu0 += wfh[0][u] * hv.x + wfh[0][u+1] * hv.y + wfh[0][u+2] * hv.z + wfh[0][u+3] * hv.w;
            pu1 += wfh[1][u] * hv.x + wfh[1][u+1] * hv.y + wfh[1][u+2] * hv.z + wfh[1][u+3] * hv.w;
        }
        float zf0 = pf0 + pu0, zf1 = pf1 + pu1;
        zf0 += __shfl_xor(zf0, 1); zf0 += __shfl_xor(zf0, 2);
        zf1 += __shfl_xor(zf1, 1); zf1 += __shfl_xor(zf1, 2);
        const float f0 = __fdividef(1.f, 1.f + __expf(-(ctxf[0] + zf0)));
        const float f1 = __fdividef(1.f, 1.f + __expf(-(ctxf[1] + zf1)));

        float hold0 = 0.f, hold1 = 0.f;
        if (act && q == 0) {
            const float2 ho = *(const float2*)&h_buf[hb][j0];
            hold0 = ho.x; hold1 = ho.y;
            float2 g2; g2.x = f0 * hold0; g2.y = f1 * hold1;
            *(float2*)&g_buf[j0] = g2;
        }
        __syncthreads();   // g visible

        // ---- phase C: v = Whh.(f*h); z_h = ph + v ----
        float pv0 = 0.f, pv1 = 0.f;
        #pragma unroll
        for (int u = 0; u < QH; u += 4) {
            const float4 gv = *(const float4*)&g_buf[q * QH + u];
            pv0 += whh[0][u] * gv.x + whh[0][u+1] * gv.y + whh[0][u+2] * gv.z + whh[0][u+3] * gv.w;
            pv1 += whh[1][u] * gv.x + whh[1][u+1] * gv.y + whh[1][u+2] * gv.z + whh[1][u+3] * gv.w;
        }
        float zh0 = ph0 + pv0, zh1 = ph1 + pv1;
        zh0 += __shfl_xor(zh0, 1); zh0 += __shfl_xor(zh0, 2);
        zh1 += __shfl_xor(zh1, 1); zh1 += __shfl_xor(zh1, 2);

        if (act && q == 0) {
            // tanh(z) = 1 - 2/(e^{2z}+1)
            const float e0 = __expf(2.f * (ctxh[0] + zh0));
            const float e1 = __expf(2.f * (ctxh[1] + zh1));
            const float th0 = 1.f - __fdividef(2.f, e0 + 1.f);
            const float th1 = 1.f - __fdividef(2.f, e1 + 1.f);
            const float hn0 = hold0 + f0 * (th0 - hold0);  // (1-f)h + f*th
            const float hn1 = hold1 + f1 * (th1 - hold1);
            *(float2*)&h_buf[hb ^ 1][j0] = make_float2(hn0, hn1);
            *(float2*)&hid[(size_t)t * NH + j0] = make_float2(hn0, hn1);
        }
        if (tid < 16 && t + 1 < NS)
            *(float4*)&x_buf[hb ^ 1][tid * 4] = xpre;
        __syncthreads();   // h_{t+1}, x_{t+1} visible
    }

    // ---- readout: output = ro_w @ h_final + ro_b ; h_final in h_buf[NS&1] = h_buf[0]
    if (tid < NO) {
        float acc = ro_b[tid];
        const float* rr = ro_w + tid * NH;
        #pragma unroll 4
        for (int i = 0; i < NH; ++i) acc += rr[i] * h_buf[0][i];
        out[b * NO + tid] = acc;
    }
}

extern "C" void kernel_launch(void* const* d_in, const int* in_sizes, int n_in,
                              void* d_out, int out_size, void* d_ws, size_t ws_size,
                              hipStream_t stream) {
    const float* x    = (const float*)d_in[0];
    const float* ctx  = (const float*)d_in[1];
    const float* Wf_w = (const float*)d_in[2];
    const float* Wf_b = (const float*)d_in[3];
    const float* Wh_w = (const float*)d_in[4];
    const float* Wh_b = (const float*)d_in[5];
    const float* ro_w = (const float*)d_in[6];
    const float* ro_b = (const float*)d_in[7];
    (void)in_sizes; (void)n_in; (void)out_size; (void)d_ws; (void)ws_size;
    agent_scan<<<dim3(NB), dim3(256), 0, stream>>>(x, ctx, Wf_w, Wf_b, Wh_w, Wh_b, ro_w, ro_b, (float*)d_out);
}

// Round 3
// 821.519 us; speedup vs baseline: 1.0354x; 1.0354x over previous
//
#include <hip/hip_runtime.h>

typedef _Float16 half2_t __attribute__((ext_vector_type(2)));

#define NB 512      // batch
#define NS 512      // seq len
#define NI 64       // input dim
#define NH 100      // hidden dim
#define NO 7        // output dim
#define WROW 168    // weight row: x(64) + ctx(4) + h(100)
#define KP 192      // padded unified K (f16 elems)
#define QK 48       // per-quarter K slice (f16 elems)
#define QP 24       // per-quarter half2 count

// v_dot2_f32_f16: acc += a.x*b.x + a.y*b.y (f32 accumulate)
__device__ __forceinline__ float dot2f(half2_t a, half2_t b, float c) {
#if defined(__gfx950__) || defined(__gfx942__) || defined(__gfx90a__) || defined(__gfx908__)
    return __builtin_amdgcn_fdot2(a, b, c, false);
#else
    return c + (float)a[0] * (float)b[0] + (float)a[1] * (float)b[1];
#endif
}

__device__ __forceinline__ half2_t pack2(float a, float b) {
    half2_t r; r[0] = (_Float16)a; r[1] = (_Float16)b; return r;
}

// One block per batch row; 256 threads: tid = jj*4 + q.
// q = K-quarter (0..3) over unified K = [x(64) | ctx-zeros(4) | h(100) | pad(24)].
// jj<50 owns outputs j0=2jj, j0+1. Weights: packed f16 in registers (96 VGPRs).
// Vectors vA=[x|h], vC=[x|g=f*h] staged in LDS as f16, double-buffered.
// Recurrence state h kept in f32 registers of the owning (q==0) thread.
__global__ __launch_bounds__(256, 2) void agent_scan(
    const float* __restrict__ x,     // [B,S,I]
    const float* __restrict__ ctx,   // [C=4]
    const float* __restrict__ Wf_w,  // [H,168]
    const float* __restrict__ Wf_b,  // [H]
    const float* __restrict__ Wh_w,  // [H,168]
    const float* __restrict__ Wh_b,  // [H]
    const float* __restrict__ ro_w,  // [O,H]
    const float* __restrict__ ro_b,  // [O]
    float* __restrict__ out)         // [B*O] ++ [B,S,H]
{
    const int b   = blockIdx.x;
    const int tid = threadIdx.x;
    const int q   = tid & 3;
    const int jj  = tid >> 2;
    const int j0  = 2 * jj;
    const bool act = (jj < NH / 2);

    __shared__ __align__(16) half2_t vA[2][KP / 2];  // [x | h | pad]
    __shared__ __align__(16) half2_t vC[2][KP / 2];  // [x | g | pad]
    __shared__ float hfin[NH];

    // zero-init both buffers (ctx slots 64..67 and pads 168..191 must stay 0)
    for (int i = tid; i < KP / 2; i += 256) {
        half2_t z = pack2(0.f, 0.f);
        vA[0][i] = z; vA[1][i] = z; vC[0][i] = z; vC[1][i] = z;
    }

    // ---- weights -> registers, packed f16. 2 outputs x 2 matrices x 24 half2 = 96 VGPR
    half2_t w[2][2][QP];          // [mat][out][pair]: mat0=Wf, mat1=Wh
    float ctxf[2], ctxh[2];
    const float c0 = ctx[0], c1 = ctx[1], c2 = ctx[2], c3 = ctx[3];
    #pragma unroll
    for (int o = 0; o < 2; ++o) {
        const int j = (j0 + o < NH) ? (j0 + o) : (NH - 1);   // clamp for inactive lanes
        const float* rf = Wf_w + (size_t)j * WROW;
        const float* rh = Wh_w + (size_t)j * WROW;
        #pragma unroll
        for (int u = 0; u < QP; ++u) {
            const int k  = q * QK + 2 * u;          // even, 0..190
            const int kk = (k <= WROW - 2) ? k : 0; // safe address
            const float s = (k <= WROW - 2) ? 1.f : 0.f;
            w[0][o][u] = pack2(rf[kk] * s, rf[kk + 1] * s);
            w[1][o][u] = pack2(rh[kk] * s, rh[kk + 1] * s);
        }
        // fold bias + ctx (v slots 64..67 are zero, so ctx contributes only here)
        ctxf[o] = Wf_b[j] + rf[64] * c0 + rf[65] * c1 + rf[66] * c2 + rf[67] * c3;
        ctxh[o] = Wh_b[j] + rh[64] * c0 + rh[65] * c1 + rh[66] * c2 + rh[67] * c3;
    }

    // stage x_0 into both buffers (f16)
    const float* xrow = x + (size_t)b * NS * NI;
    if (tid < 16) {
        float4 v4 = *(const float4*)(xrow + tid * 4);
        half2_t p0 = pack2(v4.x, v4.y), p1 = pack2(v4.z, v4.w);
        vA[0][2 * tid] = p0; vA[0][2 * tid + 1] = p1;
        vC[0][2 * tid] = p0; vC[0][2 * tid + 1] = p1;
    }
    __syncthreads();

    float h0 = 0.f, h1 = 0.f;  // owned f32 state (valid on act && q==0)
    float* hid = out + NB * NO + (size_t)b * NS * NH;

    for (int t = 0; t < NS; ++t) {
        const int cur = t & 1, nxt = cur ^ 1;

        // prefetch x_{t+1}
        float4 xp = make_float4(0.f, 0.f, 0.f, 0.f);
        if (tid < 16 && t + 1 < NS)
            xp = *(const float4*)(xrow + (size_t)(t + 1) * NI + tid * 4);

        // ---- phase A: zf = Wf . [x, h]  (per-quarter partial)
        uint4 vv[6];
        #pragma unroll
        for (int r = 0; r < 6; ++r)
            vv[r] = *(const uint4*)&vA[cur][q * QP + 4 * r];
        float a0 = 0.f, a0b = 0.f, a1 = 0.f, a1b = 0.f;
        #pragma unroll
        for (int r = 0; r < 6; ++r) {
            half2_t e0 = __builtin_bit_cast(half2_t, vv[r].x);
            half2_t e1 = __builtin_bit_cast(half2_t, vv[r].y);
            half2_t e2 = __builtin_bit_cast(half2_t, vv[r].z);
            half2_t e3 = __builtin_bit_cast(half2_t, vv[r].w);
            a0  = dot2f(w[0][0][4 * r],     e0, a0);
            a0b = dot2f(w[0][0][4 * r + 1], e1, a0b);
            a0  = dot2f(w[0][0][4 * r + 2], e2, a0);
            a0b = dot2f(w[0][0][4 * r + 3], e3, a0b);
            a1  = dot2f(w[0][1][4 * r],     e0, a1);
            a1b = dot2f(w[0][1][4 * r + 1], e1, a1b);
            a1  = dot2f(w[0][1][4 * r + 2], e2, a1);
            a1b = dot2f(w[0][1][4 * r + 3], e3, a1b);
        }
        float zf0 = a0 + a0b, zf1 = a1 + a1b;
        zf0 += __shfl_xor(zf0, 1); zf0 += __shfl_xor(zf0, 2);
        zf1 += __shfl_xor(zf1, 1); zf1 += __shfl_xor(zf1, 2);
        const float f0 = __fdividef(1.f, 1.f + __expf(-(ctxf[0] + zf0)));
        const float f1 = __fdividef(1.f, 1.f + __expf(-(ctxf[1] + zf1)));

        if (act && q == 0)
            vC[cur][34 + jj] = pack2(f0 * h0, f1 * h1);   // g at f16 idx 68+j0
        __syncthreads();   // g visible

        // ---- phase C: zh = Wh . [x, g]
        #pragma unroll
        for (int r = 0; r < 6; ++r)
            vv[r] = *(const uint4*)&vC[cur][q * QP + 4 * r];
        float b0 = 0.f, b0b = 0.f, b1 = 0.f, b1b = 0.f;
        #pragma unroll
        for (int r = 0; r < 6; ++r) {
            half2_t e0 = __builtin_bit_cast(half2_t, vv[r].x);
            half2_t e1 = __builtin_bit_cast(half2_t, vv[r].y);
            half2_t e2 = __builtin_bit_cast(half2_t, vv[r].z);
            half2_t e3 = __builtin_bit_cast(half2_t, vv[r].w);
            b0  = dot2f(w[1][0][4 * r],     e0, b0);
            b0b = dot2f(w[1][0][4 * r + 1], e1, b0b);
            b0  = dot2f(w[1][0][4 * r + 2], e2, b0);
            b0b = dot2f(w[1][0][4 * r + 3], e3, b0b);
            b1  = dot2f(w[1][1][4 * r],     e0, b1);
            b1b = dot2f(w[1][1][4 * r + 1], e1, b1b);
            b1  = dot2f(w[1][1][4 * r + 2], e2, b1);
            b1b = dot2f(w[1][1][4 * r + 3], e3, b1b);
        }
        float zh0 = b0 + b0b, zh1 = b1 + b1b;
        zh0 += __shfl_xor(zh0, 1); zh0 += __shfl_xor(zh0, 2);
        zh1 += __shfl_xor(zh1, 1); zh1 += __shfl_xor(zh1, 2);

        if (act && q == 0) {
            // tanh(z) = 1 - 2/(e^{2z}+1)
            const float e0 = __expf(2.f * (ctxh[0] + zh0));
            const float e1 = __expf(2.f * (ctxh[1] + zh1));
            const float th0 = 1.f - __fdividef(2.f, e0 + 1.f);
            const float th1 = 1.f - __fdividef(2.f, e1 + 1.f);
            h0 = h0 + f0 * (th0 - h0);   // (1-f)h + f*th, f32
            h1 = h1 + f1 * (th1 - h1);
            *(float2*)&hid[(size_t)t * NH + j0] = make_float2(h0, h1);
            vA[nxt][34 + jj] = pack2(h0, h1);            // h_{t+1} f16 copy for dots
        }
        if (tid < 16 && t + 1 < NS) {
            half2_t p0 = pack2(xp.x, xp.y), p1 = pack2(xp.z, xp.w);
            vA[nxt][2 * tid] = p0; vA[nxt][2 * tid + 1] = p1;
            vC[nxt][2 * tid] = p0; vC[nxt][2 * tid + 1] = p1;
        }
        __syncthreads();   // h_{t+1}, x_{t+1} visible
    }

    // ---- readout from f32 state
    if (act && q == 0) { hfin[j0] = h0; hfin[j0 + 1] = h1; }
    __syncthreads();
    if (tid < NO) {
        float acc = ro_b[tid];
        const float* rr = ro_w + tid * NH;
        #pragma unroll 4
        for (int i = 0; i < NH; ++i) acc += rr[i] * hfin[i];
        out[b * NO + tid] = acc;
    }
}

extern "C" void kernel_launch(void* const* d_in, const int* in_sizes, int n_in,
                              void* d_out, int out_size, void* d_ws, size_t ws_size,
                              hipStream_t stream) {
    const float* x    = (const float*)d_in[0];
    const float* ctx  = (const float*)d_in[1];
    const float* Wf_w = (const float*)d_in[2];
    const float* Wf_b = (const float*)d_in[3];
    const float* Wh_w = (const float*)d_in[4];
    const float* Wh_b = (const float*)d_in[5];
    const float* ro_w = (const float*)d_in[6];
    const float* ro_b = (const float*)d_in[7];
    (void)in_sizes; (void)n_in; (void)out_size; (void)d_ws; (void)ws_size;
    agent_scan<<<dim3(NB), dim3(256), 0, stream>>>(x, ctx, Wf_w, Wf_b, Wh_w, Wh_b, ro_w, ro_b, (float*)d_out);
}